// Round 4
// baseline (621.145 us; speedup 1.0000x reference)
//
#include <hip/hip_runtime.h>
#include <hip/hip_bf16.h>

// Problem constants (reference: B=2, N=20000, K=16, DIM=256)
// Established: float inputs are fp32 storage (R1 bf16-read gave NaN).
// R4 hypothesis: d_out is fp32 (reference output dtype float32); comparison
// itself happens in bf16 domain (label + 8*eps floor), storage is fp32.
// idx int32 vs int64 runtime-detected. mlp_init uses MFMA (distinguishable
// failure signature); final stays VALU fp32 this round.
#define BN   40000
#define NPTS 20000
#define KNN  16
#define DIM  256

typedef __attribute__((ext_vector_type(8))) short bf16x8;   // 8 bf16 = 4 VGPRs
typedef __attribute__((ext_vector_type(4))) float f32x4;

__device__ __forceinline__ float lrelu(float v) { return v > 0.f ? v : 0.1f * v; }
__device__ __forceinline__ float b2f(__hip_bfloat16 x) { return __bfloat162float(x); }
__device__ __forceinline__ short f2bs(float f) {
    __hip_bfloat16 h = __float2bfloat16(f);           // RNE
    return *reinterpret_cast<short*>(&h);
}
__device__ __forceinline__ bf16x8 ldf32_bf16x8(const float* p) {
    const float4 a = ((const float4*)p)[0];
    const float4 b = ((const float4*)p)[1];
    bf16x8 r;
    r[0]=f2bs(a.x); r[1]=f2bs(a.y); r[2]=f2bs(a.z); r[3]=f2bs(a.w);
    r[4]=f2bs(b.x); r[5]=f2bs(b.y); r[6]=f2bs(b.z); r[7]=f2bs(b.w);
    return r;
}

// ---------------------------------------------------------------------------
// idx dtype detection: int64 storage => every odd 32-bit word is 0.
// flag: 0 => int64, 1 => int32. Scan stays in-bounds under both readings.
// ---------------------------------------------------------------------------
__global__ void flag_zero_kernel(int* flag) {
    if (threadIdx.x == 0 && blockIdx.x == 0) *flag = 0;
}
__global__ void __launch_bounds__(256) detect_kernel(const int* __restrict__ idxw,
                                                     int* __restrict__ flag) {
    int t = blockIdx.x * 256 + threadIdx.x;          // t < 320000
    if (t >= 320000) return;
    if (idxw[2 * t + 1] != 0) atomicOr(flag, 1);
}

// ---------------------------------------------------------------------------
// geom MLPs (fp32 in, bf16 ws out). t1mean -> x2[:,0:64], t2mean -> x3[:,0:128]
// ---------------------------------------------------------------------------
__global__ void __launch_bounds__(256) geom_kernel(
    const float* __restrict__ geom,      // [BN,16,4]
    const float* __restrict__ W1,        // [64,4]
    const float* __restrict__ B1,        // [64]
    const float* __restrict__ W2,        // [128,4]
    const float* __restrict__ B2,        // [128]
    __hip_bfloat16* __restrict__ x2,     // [BN,128]
    __hip_bfloat16* __restrict__ x3)     // [BN,256]
{
    int tid = blockIdx.x * 256 + threadIdx.x;
    if (tid >= BN * 192) return;
    int p = tid / 192;
    int c = tid - p * 192;
    const float4* g = (const float4*)(geom + (size_t)p * (KNN * 4));
    float4 w; float bb;
    if (c < 64) { w = ((const float4*)W1)[c];      bb = B1[c]; }
    else        { int c2 = c - 64; w = ((const float4*)W2)[c2]; bb = B2[c2]; }
    float acc = 0.f;
#pragma unroll
    for (int k = 0; k < KNN; ++k) {
        float4 gv = g[k];
        acc += lrelu(bb + gv.x*w.x + gv.y*w.y + gv.z*w.z + gv.w*w.w);
    }
    acc *= (1.f/16.f);
    if (c < 64) x2[(size_t)p*128 + c]        = __float2bfloat16(acc);
    else        x3[(size_t)p*256 + (c - 64)] = __float2bfloat16(acc);
}

// ---------------------------------------------------------------------------
// x1 = LR(input @ W_init^T + b_init), [BN,256]x[64,256] -> [BN,64], MFMA.
// gemm-BT: A-frag lane holds X[m0+(l&15)][(l>>4)*8+j], B-frag same from W
// rows. C/D: col = lane&15, row = (lane>>4)*4 + reg (m89-verified mapping).
// ---------------------------------------------------------------------------
__global__ void __launch_bounds__(256) mlp_init_mfma(
    const float* __restrict__ X,     // [BN,256] fp32
    const float* __restrict__ W,     // [64,256] fp32
    const float* __restrict__ bias,  // [64]
    __hip_bfloat16* __restrict__ Y)  // [BN,64] bf16 ws
{
    int wave = threadIdx.x >> 6, lane = threadIdx.x & 63;
    int r = lane & 15, q = lane >> 4;
    int m0 = blockIdx.x * 16;
    int n0 = wave * 16;
    const float* Xs = X + (size_t)(m0 + r) * DIM + q * 8;
    const float* Ws = W + (size_t)(n0 + r) * DIM + q * 8;
    f32x4 acc = {0.f, 0.f, 0.f, 0.f};
#pragma unroll
    for (int kk = 0; kk < 8; ++kk) {
        bf16x8 a = ldf32_bf16x8(Xs + kk * 32);
        bf16x8 b = ldf32_bf16x8(Ws + kk * 32);
        acc = __builtin_amdgcn_mfma_f32_16x16x32_bf16(a, b, acc, 0, 0, 0);
    }
    float bv = bias[n0 + r];
#pragma unroll
    for (int i = 0; i < 4; ++i) {
        float v = lrelu(acc[i] + bv);
        Y[(size_t)(m0 + q*4 + i) * 64 + n0 + r] = __float2bfloat16(v);
    }
}

// ---------------------------------------------------------------------------
// gather-mean of x1 rows -> x2[:,64:128]
// ---------------------------------------------------------------------------
__global__ void __launch_bounds__(256) gather1_kernel(
    const int* __restrict__ idxw, const int* __restrict__ flag,
    const __hip_bfloat16* __restrict__ x1,    // [BN,64]
    __hip_bfloat16* __restrict__ x2)          // [BN,128]
{
    int tid = blockIdx.x * 256 + threadIdx.x;
    int p = tid >> 6, c = tid & 63;
    if (p >= BN) return;
    int dual = (*flag == 0) ? 2 : 1;
    int base = (p >= NPTS) ? NPTS : 0;
    const int* ip = idxw + (size_t)p * KNN * dual;
    float acc = 0.f;
#pragma unroll
    for (int k = 0; k < KNN; ++k) {
        int row = base + ip[k * dual];
        acc += b2f(x1[(size_t)row * 64 + c]);
    }
    x2[(size_t)p * 128 + 64 + c] = __float2bfloat16(acc * (1.f/16.f));
}

// ---------------------------------------------------------------------------
// gather-mean of x2 rows -> x3[:,128:256]
// ---------------------------------------------------------------------------
__global__ void __launch_bounds__(256) gather2_kernel(
    const int* __restrict__ idxw, const int* __restrict__ flag,
    const __hip_bfloat16* __restrict__ x2,    // [BN,128]
    __hip_bfloat16* __restrict__ x3)          // [BN,256]
{
    int tid = blockIdx.x * 256 + threadIdx.x;
    int p = tid >> 7, c = tid & 127;
    if (p >= BN) return;
    int dual = (*flag == 0) ? 2 : 1;
    int base = (p >= NPTS) ? NPTS : 0;
    const int* ip = idxw + (size_t)p * KNN * dual;
    float acc = 0.f;
#pragma unroll
    for (int k = 0; k < KNN; ++k) {
        int row = base + ip[k * dual];
        acc += b2f(x2[(size_t)row * 128 + c]);
    }
    x3[(size_t)p * 256 + 128 + c] = __float2bfloat16(acc * (1.f/16.f));
}

// ---------------------------------------------------------------------------
// out = LR(x3 @ Wf^T + bf) + LR(input @ Wi^T + bi)   VALU fp32, fp32 OUT.
// Block = 32 points; LDS-broadcast activations; W rows stream from L2.
// ---------------------------------------------------------------------------
__global__ void __launch_bounds__(256) final_valu(
    const __hip_bfloat16* __restrict__ X3,    // [BN,256] bf16 ws
    const float* __restrict__ RES,            // [BN,256]
    const float* __restrict__ Wf,             // [256,256]
    const float* __restrict__ Bf,             // [256]
    const float* __restrict__ Wi,             // [256,256]
    const float* __restrict__ Bi,             // [256]
    float* __restrict__ OUT)                  // [BN,256] fp32 !!
{
    __shared__ float xf[32][256];
    __shared__ float xr[32][256];
    int t = threadIdx.x;
    int p0 = blockIdx.x * 32;
#pragma unroll
    for (int j = 0; j < 32; ++j) {
        xf[j][t] = b2f(X3[(size_t)(p0 + j) * DIM + t]);
        xr[j][t] = RES[(size_t)(p0 + j) * DIM + t];
    }
    __syncthreads();
    int n2 = t & 127, ph = t >> 7;
    const float4* wf0 = (const float4*)(Wf + (size_t)n2 * DIM);
    const float4* wf1 = (const float4*)(Wf + (size_t)(n2 + 128) * DIM);
    const float4* wi0 = (const float4*)(Wi + (size_t)n2 * DIM);
    const float4* wi1 = (const float4*)(Wi + (size_t)(n2 + 128) * DIM);
    float af0[16], af1[16], ai0[16], ai1[16];
#pragma unroll
    for (int pp = 0; pp < 16; ++pp) { af0[pp]=0.f; af1[pp]=0.f; ai0[pp]=0.f; ai1[pp]=0.f; }
    for (int k4 = 0; k4 < 64; ++k4) {
        float4 a = wf0[k4], b = wf1[k4], c = wi0[k4], d = wi1[k4];
#pragma unroll
        for (int pp = 0; pp < 16; ++pp) {
            const float4 xv = *(const float4*)&xf[ph*16 + pp][k4*4];
            const float4 rv = *(const float4*)&xr[ph*16 + pp][k4*4];
            af0[pp] += xv.x*a.x + xv.y*a.y + xv.z*a.z + xv.w*a.w;
            af1[pp] += xv.x*b.x + xv.y*b.y + xv.z*b.z + xv.w*b.w;
            ai0[pp] += rv.x*c.x + rv.y*c.y + rv.z*c.z + rv.w*c.w;
            ai1[pp] += rv.x*d.x + rv.y*d.y + rv.z*d.z + rv.w*d.w;
        }
    }
    float bf0 = Bf[n2], bf1 = Bf[n2 + 128];
    float bi0 = Bi[n2], bi1 = Bi[n2 + 128];
#pragma unroll
    for (int pp = 0; pp < 16; ++pp) {
        size_t row = (size_t)(p0 + ph*16 + pp) * DIM;
        OUT[row + n2]       = lrelu(af0[pp] + bf0) + lrelu(ai0[pp] + bi0);
        OUT[row + n2 + 128] = lrelu(af1[pp] + bf1) + lrelu(ai1[pp] + bi1);
    }
}

// ---------------------------------------------------------------------------
extern "C" void kernel_launch(void* const* d_in, const int* in_sizes, int n_in,
                              void* d_out, int out_size, void* d_ws, size_t ws_size,
                              hipStream_t stream)
{
    const float* input  = (const float*)d_in[0];   // [2,20000,256] fp32
    const float* geom   = (const float*)d_in[1];   // [2,20000,16,4] fp32
    const int*   idxw   = (const int*)d_in[2];     // [2,20000,16] int32/int64 (detected)
    const float* W_init = (const float*)d_in[3];   // [64,256]
    const float* b_init = (const float*)d_in[4];
    const float* W_l1   = (const float*)d_in[5];   // [64,4]
    const float* b_l1   = (const float*)d_in[6];
    const float* W_l2   = (const float*)d_in[7];   // [128,4]
    const float* b_l2   = (const float*)d_in[8];
    const float* W_fin  = (const float*)d_in[9];   // [256,256]
    const float* b_fin  = (const float*)d_in[10];
    const float* W_id   = (const float*)d_in[11];  // [256,256]
    const float* b_id   = (const float*)d_in[12];
    float* out = (float*)d_out;                    // [2,20000,256] fp32 !!

    // ws: flag @0 (16B), x1 [BN,64] @16, x2 [BN,128] @16+5.12e6,
    //     x3 [BN,256] @16+15.36e6 — all fully rewritten every call.
    char* ws = (char*)d_ws;
    int* flag = (int*)ws;
    __hip_bfloat16* x1 = (__hip_bfloat16*)(ws + 16);
    __hip_bfloat16* x2 = (__hip_bfloat16*)(ws + 16 + 5120000);
    __hip_bfloat16* x3 = (__hip_bfloat16*)(ws + 16 + 15360000);

    flag_zero_kernel<<<1, 64, 0, stream>>>(flag);
    detect_kernel<<<1250, 256, 0, stream>>>(idxw, flag);
    geom_kernel<<<30000, 256, 0, stream>>>(geom, W_l1, b_l1, W_l2, b_l2, x2, x3);
    mlp_init_mfma<<<2500, 256, 0, stream>>>(input, W_init, b_init, x1);
    gather1_kernel<<<10000, 256, 0, stream>>>(idxw, flag, x1, x2);
    gather2_kernel<<<20000, 256, 0, stream>>>(idxw, flag, x2, x3);
    final_valu<<<1250, 256, 0, stream>>>(x3, input, W_fin, b_fin, W_id, b_id, out);
}

// Round 5
// 414.180 us; speedup vs baseline: 1.4997x; 1.4997x over previous
//
#include <hip/hip_runtime.h>
#include <hip/hip_bf16.h>

// Problem constants (reference: B=2, N=20000, K=16, DIM=256)
// Established facts (R1-R4):
//   - float tensors are fp32 storage; idx int32/int64 runtime-detected
//   - d_out is fp32 (reference output dtype); comparison is in bf16 domain
//   - MFMA 16x16x32_bf16 gemm-BT fragment scheme + C/D map verified (R4 pass)
#define BN   40000
#define NPTS 20000
#define KNN  16
#define DIM  256

typedef __attribute__((ext_vector_type(8))) short bf16x8;   // 8 bf16 = 4 VGPRs
typedef __attribute__((ext_vector_type(4))) float f32x4;

__device__ __forceinline__ float lrelu(float v) { return v > 0.f ? v : 0.1f * v; }
__device__ __forceinline__ float b2f(__hip_bfloat16 x) { return __bfloat162float(x); }
__device__ __forceinline__ short f2bs(float f) {
    __hip_bfloat16 h = __float2bfloat16(f);           // RNE
    return *reinterpret_cast<short*>(&h);
}
__device__ __forceinline__ bf16x8 ldf32_bf16x8(const float* p) {
    const float4 a = ((const float4*)p)[0];
    const float4 b = ((const float4*)p)[1];
    bf16x8 r;
    r[0]=f2bs(a.x); r[1]=f2bs(a.y); r[2]=f2bs(a.z); r[3]=f2bs(a.w);
    r[4]=f2bs(b.x); r[5]=f2bs(b.y); r[6]=f2bs(b.z); r[7]=f2bs(b.w);
    return r;
}

// ---------------------------------------------------------------------------
// idx dtype detection: int64 storage => every odd 32-bit word is 0.
// flag: 0 => int64, 1 => int32.
// ---------------------------------------------------------------------------
__global__ void flag_zero_kernel(int* flag) {
    if (threadIdx.x == 0 && blockIdx.x == 0) *flag = 0;
}
__global__ void __launch_bounds__(256) detect_kernel(const int* __restrict__ idxw,
                                                     int* __restrict__ flag) {
    int t = blockIdx.x * 256 + threadIdx.x;          // t < 320000
    if (t >= 320000) return;
    if (idxw[2 * t + 1] != 0) atomicOr(flag, 1);
}

// ---------------------------------------------------------------------------
// geom MLPs. Thread computes 4 consecutive channels of one point (amortizes
// the 16xfloat4 geom row reads 4x vs R4). cg<16 -> layer1 (64ch -> x2[:,0:64]),
// cg>=16 -> layer2 (128ch -> x3[:,0:128]).
// ---------------------------------------------------------------------------
__global__ void __launch_bounds__(256) geom_kernel(
    const float* __restrict__ geom,      // [BN,16,4]
    const float* __restrict__ W1,        // [64,4]
    const float* __restrict__ B1,        // [64]
    const float* __restrict__ W2,        // [128,4]
    const float* __restrict__ B2,        // [128]
    __hip_bfloat16* __restrict__ x2,     // [BN,128]
    __hip_bfloat16* __restrict__ x3)     // [BN,256]
{
    int tid = blockIdx.x * 256 + threadIdx.x;
    if (tid >= BN * 48) return;
    int p  = tid / 48;
    int cg = tid - p * 48;               // 0..47 -> 4 channels each
    const float4* g = (const float4*)(geom + (size_t)p * (KNN * 4));
    float4 w0, w1, w2, w3; float bb0, bb1, bb2, bb3;
    int c0;
    if (cg < 16) {
        c0 = cg * 4;
        w0 = ((const float4*)W1)[c0+0]; bb0 = B1[c0+0];
        w1 = ((const float4*)W1)[c0+1]; bb1 = B1[c0+1];
        w2 = ((const float4*)W1)[c0+2]; bb2 = B1[c0+2];
        w3 = ((const float4*)W1)[c0+3]; bb3 = B1[c0+3];
    } else {
        c0 = (cg - 16) * 4;
        w0 = ((const float4*)W2)[c0+0]; bb0 = B2[c0+0];
        w1 = ((const float4*)W2)[c0+1]; bb1 = B2[c0+1];
        w2 = ((const float4*)W2)[c0+2]; bb2 = B2[c0+2];
        w3 = ((const float4*)W2)[c0+3]; bb3 = B2[c0+3];
    }
    float a0 = 0.f, a1 = 0.f, a2 = 0.f, a3 = 0.f;
#pragma unroll
    for (int k = 0; k < KNN; ++k) {
        float4 gv = g[k];
        a0 += lrelu(bb0 + gv.x*w0.x + gv.y*w0.y + gv.z*w0.z + gv.w*w0.w);
        a1 += lrelu(bb1 + gv.x*w1.x + gv.y*w1.y + gv.z*w1.z + gv.w*w1.w);
        a2 += lrelu(bb2 + gv.x*w2.x + gv.y*w2.y + gv.z*w2.z + gv.w*w2.w);
        a3 += lrelu(bb3 + gv.x*w3.x + gv.y*w3.y + gv.z*w3.z + gv.w*w3.w);
    }
    const float s = 1.f/16.f;
    __hip_bfloat16* dst = (cg < 16) ? (x2 + (size_t)p*128 + c0)
                                    : (x3 + (size_t)p*256 + c0);
    dst[0] = __float2bfloat16(a0 * s);
    dst[1] = __float2bfloat16(a1 * s);
    dst[2] = __float2bfloat16(a2 * s);
    dst[3] = __float2bfloat16(a3 * s);
}

// ---------------------------------------------------------------------------
// x1 = LR(input @ W_init^T + b_init), [BN,256]x[64,256] -> [BN,64], MFMA.
// Verified R4. fp32 in-register converts (amortization fine at this size).
// ---------------------------------------------------------------------------
__global__ void __launch_bounds__(256) mlp_init_mfma(
    const float* __restrict__ X,     // [BN,256]
    const float* __restrict__ W,     // [64,256]
    const float* __restrict__ bias,  // [64]
    __hip_bfloat16* __restrict__ Y)  // [BN,64] bf16 ws
{
    int wave = threadIdx.x >> 6, lane = threadIdx.x & 63;
    int r = lane & 15, q = lane >> 4;
    int m0 = blockIdx.x * 16;
    int n0 = wave * 16;
    const float* Xs = X + (size_t)(m0 + r) * DIM + q * 8;
    const float* Ws = W + (size_t)(n0 + r) * DIM + q * 8;
    f32x4 acc = {0.f, 0.f, 0.f, 0.f};
#pragma unroll
    for (int kk = 0; kk < 8; ++kk) {
        bf16x8 a = ldf32_bf16x8(Xs + kk * 32);
        bf16x8 b = ldf32_bf16x8(Ws + kk * 32);
        acc = __builtin_amdgcn_mfma_f32_16x16x32_bf16(a, b, acc, 0, 0, 0);
    }
    float bv = bias[n0 + r];
#pragma unroll
    for (int i = 0; i < 4; ++i) {
        float v = lrelu(acc[i] + bv);
        Y[(size_t)(m0 + q*4 + i) * 64 + n0 + r] = __float2bfloat16(v);
    }
}

// ---------------------------------------------------------------------------
// gather-mean of x1 rows -> x2[:,64:128]
// ---------------------------------------------------------------------------
__global__ void __launch_bounds__(256) gather1_kernel(
    const int* __restrict__ idxw, const int* __restrict__ flag,
    const __hip_bfloat16* __restrict__ x1,    // [BN,64]
    __hip_bfloat16* __restrict__ x2)          // [BN,128]
{
    int tid = blockIdx.x * 256 + threadIdx.x;
    int p = tid >> 6, c = tid & 63;
    if (p >= BN) return;
    int dual = (*flag == 0) ? 2 : 1;
    int base = (p >= NPTS) ? NPTS : 0;
    const int* ip = idxw + (size_t)p * KNN * dual;
    float acc = 0.f;
#pragma unroll
    for (int k = 0; k < KNN; ++k) {
        int row = base + ip[k * dual];
        acc += b2f(x1[(size_t)row * 64 + c]);
    }
    x2[(size_t)p * 128 + 64 + c] = __float2bfloat16(acc * (1.f/16.f));
}

// ---------------------------------------------------------------------------
// gather-mean of x2 rows -> x3[:,128:256]
// ---------------------------------------------------------------------------
__global__ void __launch_bounds__(256) gather2_kernel(
    const int* __restrict__ idxw, const int* __restrict__ flag,
    const __hip_bfloat16* __restrict__ x2,    // [BN,128]
    __hip_bfloat16* __restrict__ x3)          // [BN,256]
{
    int tid = blockIdx.x * 256 + threadIdx.x;
    int p = tid >> 7, c = tid & 127;
    if (p >= BN) return;
    int dual = (*flag == 0) ? 2 : 1;
    int base = (p >= NPTS) ? NPTS : 0;
    const int* ip = idxw + (size_t)p * KNN * dual;
    float acc = 0.f;
#pragma unroll
    for (int k = 0; k < KNN; ++k) {
        int row = base + ip[k * dual];
        acc += b2f(x2[(size_t)row * 128 + c]);
    }
    x3[(size_t)p * 256 + 128 + c] = __float2bfloat16(acc * (1.f/16.f));
}

// ---------------------------------------------------------------------------
// Convert W_fin + W_id (fp32 [256,256]) to bf16 into the dead x1 region.
// Runs after gather1 (x1 no longer needed), before final_mfma.
// ---------------------------------------------------------------------------
__global__ void __launch_bounds__(256) conv_w_kernel(
    const float* __restrict__ Wf, const float* __restrict__ Wi,
    short* __restrict__ Wfb, short* __restrict__ Wib)
{
    int t = blockIdx.x * 256 + threadIdx.x;     // 32768 float4 total
    if (t >= 32768) return;
    const float4 v = (t < 16384) ? ((const float4*)Wf)[t] : ((const float4*)Wi)[t - 16384];
    short4 o;
    o.x = f2bs(v.x); o.y = f2bs(v.y); o.z = f2bs(v.z); o.w = f2bs(v.w);
    if (t < 16384) ((short4*)Wfb)[t] = o;
    else           ((short4*)Wib)[t - 16384] = o;
}

// ---------------------------------------------------------------------------
// out = LR(x3 @ Wf^T + bf) + LR(input @ Wi^T + bi), fp32 out. MFMA.
// Block = 64 M-rows (4 waves x 16); each wave computes 16 rows x full N=256
// (16 n-tiles, 2 GEMMs => 128 acc VGPRs). K outer: A-frags loaded/converted
// once per kk, reused across 16 n-tiles; weights pre-converted bf16 (no
// in-loop cvt on the B side). Weight tiles identical across the 4 waves ->
// L1/L2 reuse; 625 blocks x 256 KB unique = 160 MB L2 traffic.
// ---------------------------------------------------------------------------
__global__ void __launch_bounds__(256) final_mfma(
    const __hip_bfloat16* __restrict__ X3,    // [BN,256] bf16 ws
    const float* __restrict__ RES,            // [BN,256] fp32
    const short* __restrict__ Wfb,            // [256,256] bf16
    const float* __restrict__ Bf,             // [256]
    const short* __restrict__ Wib,            // [256,256] bf16
    const float* __restrict__ Bi,             // [256]
    float* __restrict__ OUT)                  // [BN,256] fp32
{
    int wave = threadIdx.x >> 6, lane = threadIdx.x & 63;
    int r = lane & 15, q = lane >> 4;
    int m0 = blockIdx.x * 64 + wave * 16;
    const short* As = (const short*)X3 + (size_t)(m0 + r) * DIM + q * 8;
    const float* Rs = RES + (size_t)(m0 + r) * DIM + q * 8;
    const short* Wf0 = Wfb + (size_t)r * DIM + q * 8;   // + nt*16*DIM + kk*32
    const short* Wi0 = Wib + (size_t)r * DIM + q * 8;

    f32x4 acc1[16], acc2[16];
#pragma unroll
    for (int nt = 0; nt < 16; ++nt) {
        acc1[nt] = (f32x4){0.f,0.f,0.f,0.f};
        acc2[nt] = (f32x4){0.f,0.f,0.f,0.f};
    }
#pragma unroll
    for (int kk = 0; kk < 8; ++kk) {
        bf16x8 a1 = *(const bf16x8*)(As + kk * 32);
        bf16x8 a2 = ldf32_bf16x8(Rs + kk * 32);
#pragma unroll
        for (int nt = 0; nt < 16; ++nt) {
            bf16x8 b1 = *(const bf16x8*)(Wf0 + (size_t)nt * (16 * DIM) + kk * 32);
            bf16x8 b2 = *(const bf16x8*)(Wi0 + (size_t)nt * (16 * DIM) + kk * 32);
            acc1[nt] = __builtin_amdgcn_mfma_f32_16x16x32_bf16(a1, b1, acc1[nt], 0, 0, 0);
            acc2[nt] = __builtin_amdgcn_mfma_f32_16x16x32_bf16(a2, b2, acc2[nt], 0, 0, 0);
        }
    }
#pragma unroll
    for (int nt = 0; nt < 16; ++nt) {
        int col = nt * 16 + r;
        float bfv = Bf[col], biv = Bi[col];
#pragma unroll
        for (int i = 0; i < 4; ++i) {
            float v = lrelu(acc1[nt][i] + bfv) + lrelu(acc2[nt][i] + biv);
            OUT[(size_t)(m0 + q*4 + i) * DIM + col] = v;
        }
    }
}

// ---------------------------------------------------------------------------
extern "C" void kernel_launch(void* const* d_in, const int* in_sizes, int n_in,
                              void* d_out, int out_size, void* d_ws, size_t ws_size,
                              hipStream_t stream)
{
    const float* input  = (const float*)d_in[0];   // [2,20000,256]
    const float* geom   = (const float*)d_in[1];   // [2,20000,16,4]
    const int*   idxw   = (const int*)d_in[2];     // int32/int64 (detected)
    const float* W_init = (const float*)d_in[3];   // [64,256]
    const float* b_init = (const float*)d_in[4];
    const float* W_l1   = (const float*)d_in[5];   // [64,4]
    const float* b_l1   = (const float*)d_in[6];
    const float* W_l2   = (const float*)d_in[7];   // [128,4]
    const float* b_l2   = (const float*)d_in[8];
    const float* W_fin  = (const float*)d_in[9];   // [256,256]
    const float* b_fin  = (const float*)d_in[10];
    const float* W_id   = (const float*)d_in[11];  // [256,256]
    const float* b_id   = (const float*)d_in[12];
    float* out = (float*)d_out;                    // [2,20000,256] fp32

    // ws (proven safe <= 35.84 MB in R4):
    //   flag @0 (16B)
    //   x1  [BN,64]  bf16 @16            — dead after gather1; conv_w reuses it
    //   x2  [BN,128] bf16 @16+5.12e6
    //   x3  [BN,256] bf16 @16+15.36e6
    char* ws = (char*)d_ws;
    int* flag = (int*)ws;
    __hip_bfloat16* x1 = (__hip_bfloat16*)(ws + 16);
    __hip_bfloat16* x2 = (__hip_bfloat16*)(ws + 16 + 5120000);
    __hip_bfloat16* x3 = (__hip_bfloat16*)(ws + 16 + 15360000);
    short* Wfb = (short*)(ws + 16);                 // 131072 B
    short* Wib = (short*)(ws + 16 + 131072);        // 131072 B  (within old x1)

    flag_zero_kernel<<<1, 64, 0, stream>>>(flag);
    detect_kernel<<<1250, 256, 0, stream>>>(idxw, flag);
    geom_kernel<<<7500, 256, 0, stream>>>(geom, W_l1, b_l1, W_l2, b_l2, x2, x3);
    mlp_init_mfma<<<2500, 256, 0, stream>>>(input, W_init, b_init, x1);
    gather1_kernel<<<10000, 256, 0, stream>>>(idxw, flag, x1, x2);
    gather2_kernel<<<20000, 256, 0, stream>>>(idxw, flag, x2, x3);
    conv_w_kernel<<<128, 256, 0, stream>>>(W_fin, W_id, Wfb, Wib);
    final_mfma<<<625, 256, 0, stream>>>(x3, input, Wfb, b_fin, Wib, b_id, out);
}

// Round 6
// 376.283 us; speedup vs baseline: 1.6507x; 1.1007x over previous
//
#include <hip/hip_runtime.h>
#include <hip/hip_bf16.h>

// Problem constants (reference: B=2, N=20000, K=16, DIM=256)
// Established facts (R1-R5):
//   - float tensors fp32; idx int32/int64 runtime-detected; d_out fp32
//   - MFMA 16x16x32_bf16 gemm-BT fragments + C/D map verified (R4/R5 pass)
//   - R5 lesson: 128 acc VGPRs starve load buffering -> latency-bound (Mfma 3%)
//     => keep acc <= 32 VGPRs/wave, split N across blocks for grid size.
#define BN   40000
#define NPTS 20000
#define KNN  16
#define DIM  256

typedef __attribute__((ext_vector_type(8))) short bf16x8;   // 8 bf16 = 4 VGPRs
typedef __attribute__((ext_vector_type(4))) float f32x4;

__device__ __forceinline__ float lrelu(float v) { return v > 0.f ? v : 0.1f * v; }
__device__ __forceinline__ float bs2f(short s) {
    union { unsigned u; float f; } c; c.u = ((unsigned)(unsigned short)s) << 16;
    return c.f;
}
__device__ __forceinline__ short f2bs(float f) {
    __hip_bfloat16 h = __float2bfloat16(f);           // RNE
    return *reinterpret_cast<short*>(&h);
}
__device__ __forceinline__ bf16x8 ldf32_bf16x8(const float* p) {
    const float4 a = ((const float4*)p)[0];
    const float4 b = ((const float4*)p)[1];
    bf16x8 r;
    r[0]=f2bs(a.x); r[1]=f2bs(a.y); r[2]=f2bs(a.z); r[3]=f2bs(a.w);
    r[4]=f2bs(b.x); r[5]=f2bs(b.y); r[6]=f2bs(b.z); r[7]=f2bs(b.w);
    return r;
}

// ---------------------------------------------------------------------------
// idx dtype detection: int64 storage => every odd 32-bit word is 0.
// flag: 0 => int64, 1 => int32.
// ---------------------------------------------------------------------------
__global__ void flag_zero_kernel(int* flag) {
    if (threadIdx.x == 0 && blockIdx.x == 0) *flag = 0;
}
__global__ void __launch_bounds__(256) detect_kernel(const int* __restrict__ idxw,
                                                     int* __restrict__ flag) {
    int t = blockIdx.x * 256 + threadIdx.x;          // t < 320000
    if (t >= 320000) return;
    if (idxw[2 * t + 1] != 0) atomicOr(flag, 1);
}

// ---------------------------------------------------------------------------
// geom MLPs. 12 threads/point, 16 channels each (weights hoisted to VGPRs).
// cg<4 -> layer1 (64ch -> x2[:,0:64]); cg>=4 -> layer2 (128ch -> x3[:,0:128]).
// Redundant geom-row traffic: 12 x 256B = 3 KB/point (was 12 KB in R5).
// ---------------------------------------------------------------------------
__global__ void __launch_bounds__(256) geom_kernel(
    const float* __restrict__ geom,      // [BN,16,4]
    const float* __restrict__ W1,        // [64,4]
    const float* __restrict__ B1,        // [64]
    const float* __restrict__ W2,        // [128,4]
    const float* __restrict__ B2,        // [128]
    __hip_bfloat16* __restrict__ x2,     // [BN,128]
    __hip_bfloat16* __restrict__ x3)     // [BN,256]
{
    int tid = blockIdx.x * 256 + threadIdx.x;
    if (tid >= BN * 12) return;
    int p  = tid / 12;
    int cg = tid - p * 12;               // 0..11 -> 16 channels each
    const float4* g = (const float4*)(geom + (size_t)p * (KNN * 4));
    const float4* Wp; const float* Bp; int c0;
    if (cg < 4) { c0 = cg * 16;       Wp = (const float4*)W1; Bp = B1; }
    else        { c0 = (cg - 4) * 16; Wp = (const float4*)W2; Bp = B2; }
    float4 w[16]; float bb[16];
#pragma unroll
    for (int j = 0; j < 16; ++j) { w[j] = Wp[c0 + j]; bb[j] = Bp[c0 + j]; }
    float acc[16];
#pragma unroll
    for (int j = 0; j < 16; ++j) acc[j] = 0.f;
#pragma unroll
    for (int k = 0; k < KNN; ++k) {
        float4 gv = g[k];
#pragma unroll
        for (int j = 0; j < 16; ++j)
            acc[j] += lrelu(bb[j] + gv.x*w[j].x + gv.y*w[j].y + gv.z*w[j].z + gv.w*w[j].w);
    }
    const float s = 1.f/16.f;
    short* dst = (cg < 4) ? ((short*)x2 + (size_t)p*128 + c0)
                          : ((short*)x3 + (size_t)p*256 + c0);
    bf16x8 o0, o1;
#pragma unroll
    for (int j = 0; j < 8; ++j) { o0[j] = f2bs(acc[j] * s); o1[j] = f2bs(acc[j+8] * s); }
    *(bf16x8*)(dst)     = o0;
    *(bf16x8*)(dst + 8) = o1;
}

// ---------------------------------------------------------------------------
// x1 = LR(input @ W_init^T + b_init), [BN,256]x[64,256] -> [BN,64], MFMA.
// Block = 64 rows (4 waves x 16); wave covers all 64 n (4 nt): A-frag reused
// 4x, acc = 16 VGPRs. Grid 625.
// ---------------------------------------------------------------------------
__global__ void __launch_bounds__(256) mlp_init_mfma(
    const float* __restrict__ X,     // [BN,256]
    const float* __restrict__ W,     // [64,256]
    const float* __restrict__ bias,  // [64]
    __hip_bfloat16* __restrict__ Y)  // [BN,64] bf16 ws
{
    int wave = threadIdx.x >> 6, lane = threadIdx.x & 63;
    int r = lane & 15, q = lane >> 4;
    int m0 = blockIdx.x * 64 + wave * 16;
    const float* Xs = X + (size_t)(m0 + r) * DIM + q * 8;
    const float* W0 = W + (size_t)r * DIM + q * 8;     // + nt*16*DIM + kk*32
    f32x4 acc[4];
#pragma unroll
    for (int nt = 0; nt < 4; ++nt) acc[nt] = (f32x4){0.f,0.f,0.f,0.f};
#pragma unroll
    for (int kk = 0; kk < 8; ++kk) {
        bf16x8 a = ldf32_bf16x8(Xs + kk * 32);
#pragma unroll
        for (int nt = 0; nt < 4; ++nt) {
            bf16x8 b = ldf32_bf16x8(W0 + (size_t)nt * (16 * DIM) + kk * 32);
            acc[nt] = __builtin_amdgcn_mfma_f32_16x16x32_bf16(a, b, acc[nt], 0, 0, 0);
        }
    }
#pragma unroll
    for (int nt = 0; nt < 4; ++nt) {
        int col = nt * 16 + r;
        float bv = bias[col];
#pragma unroll
        for (int i = 0; i < 4; ++i) {
            float v = lrelu(acc[nt][i] + bv);
            Y[(size_t)(m0 + q*4 + i) * 64 + col] = __float2bfloat16(v);
        }
    }
}

// ---------------------------------------------------------------------------
// gather-mean of x1 rows -> x2[:,64:128]. 8 lanes/point, bf16x8 (16B) loads.
// ---------------------------------------------------------------------------
__global__ void __launch_bounds__(256) gather1_kernel(
    const int* __restrict__ idxw, const int* __restrict__ flag,
    const __hip_bfloat16* __restrict__ x1,    // [BN,64]
    __hip_bfloat16* __restrict__ x2)          // [BN,128]
{
    int t = blockIdx.x * 256 + threadIdx.x;
    int p = t >> 3, j = t & 7;
    if (p >= BN) return;
    int dual = (*flag == 0) ? 2 : 1;
    int base = (p >= NPTS) ? NPTS : 0;
    const int* ip = idxw + (size_t)p * KNN * dual;
    float acc[8];
#pragma unroll
    for (int i = 0; i < 8; ++i) acc[i] = 0.f;
#pragma unroll
    for (int k = 0; k < KNN; ++k) {
        int row = base + ip[k * dual];
        bf16x8 v = *(const bf16x8*)((const short*)x1 + (size_t)row * 64 + j * 8);
#pragma unroll
        for (int i = 0; i < 8; ++i) acc[i] += bs2f(v[i]);
    }
    bf16x8 o;
#pragma unroll
    for (int i = 0; i < 8; ++i) o[i] = f2bs(acc[i] * (1.f/16.f));
    *(bf16x8*)((short*)x2 + (size_t)p * 128 + 64 + j * 8) = o;
}

// ---------------------------------------------------------------------------
// gather-mean of x2 rows -> x3[:,128:256]. 16 lanes/point, bf16x8 loads.
// ---------------------------------------------------------------------------
__global__ void __launch_bounds__(256) gather2_kernel(
    const int* __restrict__ idxw, const int* __restrict__ flag,
    const __hip_bfloat16* __restrict__ x2,    // [BN,128]
    __hip_bfloat16* __restrict__ x3)          // [BN,256]
{
    int t = blockIdx.x * 256 + threadIdx.x;
    int p = t >> 4, j = t & 15;
    if (p >= BN) return;
    int dual = (*flag == 0) ? 2 : 1;
    int base = (p >= NPTS) ? NPTS : 0;
    const int* ip = idxw + (size_t)p * KNN * dual;
    float acc[8];
#pragma unroll
    for (int i = 0; i < 8; ++i) acc[i] = 0.f;
#pragma unroll
    for (int k = 0; k < KNN; ++k) {
        int row = base + ip[k * dual];
        bf16x8 v = *(const bf16x8*)((const short*)x2 + (size_t)row * 128 + j * 8);
#pragma unroll
        for (int i = 0; i < 8; ++i) acc[i] += bs2f(v[i]);
    }
    bf16x8 o;
#pragma unroll
    for (int i = 0; i < 8; ++i) o[i] = f2bs(acc[i] * (1.f/16.f));
    *(bf16x8*)((short*)x3 + (size_t)p * 256 + 128 + j * 8) = o;
}

// ---------------------------------------------------------------------------
// Convert W_fin + W_id (fp32 [256,256]) to bf16 into the dead x1 region.
// Runs after gather1 (x1 no longer needed), before final_mfma.
// ---------------------------------------------------------------------------
__global__ void __launch_bounds__(256) conv_w_kernel(
    const float* __restrict__ Wf, const float* __restrict__ Wi,
    short* __restrict__ Wfb, short* __restrict__ Wib)
{
    int t = blockIdx.x * 256 + threadIdx.x;     // 32768 float4 total
    if (t >= 32768) return;
    const float4 v = (t < 16384) ? ((const float4*)Wf)[t] : ((const float4*)Wi)[t - 16384];
    short4 o;
    o.x = f2bs(v.x); o.y = f2bs(v.y); o.z = f2bs(v.z); o.w = f2bs(v.w);
    if (t < 16384) ((short4*)Wfb)[t] = o;
    else           ((short4*)Wib)[t - 16384] = o;
}

// ---------------------------------------------------------------------------
// out = LR(x3 @ Wf^T + bf) + LR(input @ Wi^T + bi), fp32 out. MFMA.
// Grid (625, 4): block = 64 rows x 64 cols. Wave = 16 rows x 64 cols
// (4 nt x 2 GEMMs = 32 acc VGPRs, ~100 spare for in-flight loads).
// A re-read 4x across blockIdx.y -> L3-resident (61 MB << 256 MB).
// ---------------------------------------------------------------------------
__global__ void __launch_bounds__(256) final_mfma(
    const __hip_bfloat16* __restrict__ X3,    // [BN,256] bf16 ws
    const float* __restrict__ RES,            // [BN,256] fp32
    const short* __restrict__ Wfb,            // [256,256] bf16
    const float* __restrict__ Bf,             // [256]
    const short* __restrict__ Wib,            // [256,256] bf16
    const float* __restrict__ Bi,             // [256]
    float* __restrict__ OUT)                  // [BN,256] fp32
{
    int wave = threadIdx.x >> 6, lane = threadIdx.x & 63;
    int r = lane & 15, q = lane >> 4;
    int m0 = blockIdx.x * 64 + wave * 16;
    int n0 = blockIdx.y * 64;
    const short* As = (const short*)X3 + (size_t)(m0 + r) * DIM + q * 8;
    const float* Rs = RES + (size_t)(m0 + r) * DIM + q * 8;
    const short* Wf0 = Wfb + (size_t)(n0 + r) * DIM + q * 8;   // + nt*16*DIM + kk*32
    const short* Wi0 = Wib + (size_t)(n0 + r) * DIM + q * 8;

    f32x4 acc1[4], acc2[4];
#pragma unroll
    for (int nt = 0; nt < 4; ++nt) {
        acc1[nt] = (f32x4){0.f,0.f,0.f,0.f};
        acc2[nt] = (f32x4){0.f,0.f,0.f,0.f};
    }
#pragma unroll
    for (int kk = 0; kk < 8; ++kk) {
        bf16x8 a1 = *(const bf16x8*)(As + kk * 32);
        bf16x8 a2 = ldf32_bf16x8(Rs + kk * 32);
#pragma unroll
        for (int nt = 0; nt < 4; ++nt) {
            bf16x8 b1 = *(const bf16x8*)(Wf0 + (size_t)nt * (16 * DIM) + kk * 32);
            bf16x8 b2 = *(const bf16x8*)(Wi0 + (size_t)nt * (16 * DIM) + kk * 32);
            acc1[nt] = __builtin_amdgcn_mfma_f32_16x16x32_bf16(a1, b1, acc1[nt], 0, 0, 0);
            acc2[nt] = __builtin_amdgcn_mfma_f32_16x16x32_bf16(a2, b2, acc2[nt], 0, 0, 0);
        }
    }
#pragma unroll
    for (int nt = 0; nt < 4; ++nt) {
        int col = n0 + nt * 16 + r;
        float bfv = Bf[col], biv = Bi[col];
#pragma unroll
        for (int i = 0; i < 4; ++i) {
            float v = lrelu(acc1[nt][i] + bfv) + lrelu(acc2[nt][i] + biv);
            OUT[(size_t)(m0 + q*4 + i) * DIM + col] = v;
        }
    }
}

// ---------------------------------------------------------------------------
extern "C" void kernel_launch(void* const* d_in, const int* in_sizes, int n_in,
                              void* d_out, int out_size, void* d_ws, size_t ws_size,
                              hipStream_t stream)
{
    const float* input  = (const float*)d_in[0];   // [2,20000,256]
    const float* geom   = (const float*)d_in[1];   // [2,20000,16,4]
    const int*   idxw   = (const int*)d_in[2];     // int32/int64 (detected)
    const float* W_init = (const float*)d_in[3];   // [64,256]
    const float* b_init = (const float*)d_in[4];
    const float* W_l1   = (const float*)d_in[5];   // [64,4]
    const float* b_l1   = (const float*)d_in[6];
    const float* W_l2   = (const float*)d_in[7];   // [128,4]
    const float* b_l2   = (const float*)d_in[8];
    const float* W_fin  = (const float*)d_in[9];   // [256,256]
    const float* b_fin  = (const float*)d_in[10];
    const float* W_id   = (const float*)d_in[11];  // [256,256]
    const float* b_id   = (const float*)d_in[12];
    float* out = (float*)d_out;                    // [2,20000,256] fp32

    // ws (proven safe <= 35.84 MB in R4/R5):
    //   flag @0 (16B)
    //   x1  [BN,64]  bf16 @16            — dead after gather1; conv_w reuses it
    //   x2  [BN,128] bf16 @16+5.12e6
    //   x3  [BN,256] bf16 @16+15.36e6
    char* ws = (char*)d_ws;
    int* flag = (int*)ws;
    __hip_bfloat16* x1 = (__hip_bfloat16*)(ws + 16);
    __hip_bfloat16* x2 = (__hip_bfloat16*)(ws + 16 + 5120000);
    __hip_bfloat16* x3 = (__hip_bfloat16*)(ws + 16 + 15360000);
    short* Wfb = (short*)(ws + 16);                 // 131072 B
    short* Wib = (short*)(ws + 16 + 131072);        // 131072 B  (within old x1)

    flag_zero_kernel<<<1, 64, 0, stream>>>(flag);
    detect_kernel<<<1250, 256, 0, stream>>>(idxw, flag);
    geom_kernel<<<1875, 256, 0, stream>>>(geom, W_l1, b_l1, W_l2, b_l2, x2, x3);
    mlp_init_mfma<<<625, 256, 0, stream>>>(input, W_init, b_init, x1);
    gather1_kernel<<<1250, 256, 0, stream>>>(idxw, flag, x1, x2);
    gather2_kernel<<<2500, 256, 0, stream>>>(idxw, flag, x2, x3);
    conv_w_kernel<<<128, 256, 0, stream>>>(W_fin, W_id, Wfb, Wib);
    final_mfma<<<dim3(625, 4), 256, 0, stream>>>(x3, input, Wfb, b_fin, Wib, b_id, out);
}

// Round 7
// 294.604 us; speedup vs baseline: 2.1084x; 1.2773x over previous
//
#include <hip/hip_runtime.h>
#include <hip/hip_bf16.h>

// Problem constants (reference: B=2, N=20000, K=16, DIM=256)
// Established facts (R1-R6):
//   - float tensors fp32; idx int32/int64 runtime-detected; d_out fp32
//   - MFMA 16x16x32_bf16 gemm-BT fragments + C/D map verified (R4/R5/R6 pass)
//   - R5: >64 acc VGPRs/wave starves load buffering -> latency-bound
//   - R6: N-split across blocks re-fetches A 4x (FETCH 33->140 MB) -> this
//     round: full-N blocks with LDS-shared A rows (unique fetch, small acc)
#define BN   40000
#define NPTS 20000
#define KNN  16
#define DIM  256

typedef __attribute__((ext_vector_type(8))) short bf16x8;   // 8 bf16 = 4 VGPRs
typedef __attribute__((ext_vector_type(4))) float f32x4;

__device__ __forceinline__ float lrelu(float v) { return v > 0.f ? v : 0.1f * v; }
__device__ __forceinline__ float bs2f(short s) {
    union { unsigned u; float f; } c; c.u = ((unsigned)(unsigned short)s) << 16;
    return c.f;
}
__device__ __forceinline__ short f2bs(float f) {
    __hip_bfloat16 h = __float2bfloat16(f);           // RNE
    return *reinterpret_cast<short*>(&h);
}
__device__ __forceinline__ bf16x8 ldf32_bf16x8(const float* p) {
    const float4 a = ((const float4*)p)[0];
    const float4 b = ((const float4*)p)[1];
    bf16x8 r;
    r[0]=f2bs(a.x); r[1]=f2bs(a.y); r[2]=f2bs(a.z); r[3]=f2bs(a.w);
    r[4]=f2bs(b.x); r[5]=f2bs(b.y); r[6]=f2bs(b.z); r[7]=f2bs(b.w);
    return r;
}

// ---------------------------------------------------------------------------
// geom MLPs + embedded idx-dtype detection (block 1875).
// geom: 12 threads/point, 16 channels each. cg<4 -> layer1 (x2[:,0:64]);
// cg>=4 -> layer2 (x3[:,0:128]).
// detect (single block, no atomics): scan first 16384 int64-candidate slots;
// if all odd 32-bit words are 0 => int64 storage (flag=0), else int32 (flag=1).
// ---------------------------------------------------------------------------
__global__ void __launch_bounds__(256) geom_kernel(
    const float* __restrict__ geom,      // [BN,16,4]
    const float* __restrict__ W1,        // [64,4]
    const float* __restrict__ B1,        // [64]
    const float* __restrict__ W2,        // [128,4]
    const float* __restrict__ B2,        // [128]
    const int* __restrict__ idxw,        // int32 view of idx buffer
    int* __restrict__ flag,
    __hip_bfloat16* __restrict__ x2,     // [BN,128]
    __hip_bfloat16* __restrict__ x3)     // [BN,256]
{
    if (blockIdx.x == 1875) {            // ---- detect block ----
        __shared__ int red[256];
        int t = threadIdx.x;
        int v = 0;
#pragma unroll
        for (int it = 0; it < 64; ++it)
            v |= idxw[2 * (t + it * 256) + 1];       // odd words, first 128 KB
        red[t] = v;
        __syncthreads();
        for (int s = 128; s > 0; s >>= 1) {
            if (t < s) red[t] |= red[t + s];
            __syncthreads();
        }
        if (t == 0) *flag = (red[0] != 0) ? 1 : 0;
        return;
    }
    int tid = blockIdx.x * 256 + threadIdx.x;        // < 480000 exactly
    int p  = tid / 12;
    int cg = tid - p * 12;               // 0..11 -> 16 channels each
    const float4* g = (const float4*)(geom + (size_t)p * (KNN * 4));
    const float4* Wp; const float* Bp; int c0;
    if (cg < 4) { c0 = cg * 16;       Wp = (const float4*)W1; Bp = B1; }
    else        { c0 = (cg - 4) * 16; Wp = (const float4*)W2; Bp = B2; }
    float4 w[16]; float bb[16];
#pragma unroll
    for (int j = 0; j < 16; ++j) { w[j] = Wp[c0 + j]; bb[j] = Bp[c0 + j]; }
    float acc[16];
#pragma unroll
    for (int j = 0; j < 16; ++j) acc[j] = 0.f;
#pragma unroll
    for (int k = 0; k < KNN; ++k) {
        float4 gv = g[k];
#pragma unroll
        for (int j = 0; j < 16; ++j)
            acc[j] += lrelu(bb[j] + gv.x*w[j].x + gv.y*w[j].y + gv.z*w[j].z + gv.w*w[j].w);
    }
    const float s = 1.f/16.f;
    short* dst = (cg < 4) ? ((short*)x2 + (size_t)p*128 + c0)
                          : ((short*)x3 + (size_t)p*256 + c0);
    bf16x8 o0, o1;
#pragma unroll
    for (int j = 0; j < 8; ++j) { o0[j] = f2bs(acc[j] * s); o1[j] = f2bs(acc[j+8] * s); }
    *(bf16x8*)(dst)     = o0;
    *(bf16x8*)(dst + 8) = o1;
}

// ---------------------------------------------------------------------------
// x1 = LR(input @ W_init^T + b_init), [BN,256]x[64,256] -> [BN,64], MFMA.
// Block = 64 rows (4 waves x 16); wave covers all 64 n (4 nt). Grid 625.
// ---------------------------------------------------------------------------
__global__ void __launch_bounds__(256) mlp_init_mfma(
    const float* __restrict__ X,     // [BN,256]
    const float* __restrict__ W,     // [64,256]
    const float* __restrict__ bias,  // [64]
    __hip_bfloat16* __restrict__ Y)  // [BN,64] bf16 ws
{
    int wave = threadIdx.x >> 6, lane = threadIdx.x & 63;
    int r = lane & 15, q = lane >> 4;
    int m0 = blockIdx.x * 64 + wave * 16;
    const float* Xs = X + (size_t)(m0 + r) * DIM + q * 8;
    const float* W0 = W + (size_t)r * DIM + q * 8;     // + nt*16*DIM + kk*32
    f32x4 acc[4];
#pragma unroll
    for (int nt = 0; nt < 4; ++nt) acc[nt] = (f32x4){0.f,0.f,0.f,0.f};
#pragma unroll
    for (int kk = 0; kk < 8; ++kk) {
        bf16x8 a = ldf32_bf16x8(Xs + kk * 32);
#pragma unroll
        for (int nt = 0; nt < 4; ++nt) {
            bf16x8 b = ldf32_bf16x8(W0 + (size_t)nt * (16 * DIM) + kk * 32);
            acc[nt] = __builtin_amdgcn_mfma_f32_16x16x32_bf16(a, b, acc[nt], 0, 0, 0);
        }
    }
#pragma unroll
    for (int nt = 0; nt < 4; ++nt) {
        int col = nt * 16 + r;
        float bv = bias[col];
#pragma unroll
        for (int i = 0; i < 4; ++i) {
            float v = lrelu(acc[nt][i] + bv);
            Y[(size_t)(m0 + q*4 + i) * 64 + col] = __float2bfloat16(v);
        }
    }
}

// ---------------------------------------------------------------------------
// gather-mean of x1 rows -> x2[:,64:128]. 8 lanes/point, bf16x8 (16B) loads.
// ---------------------------------------------------------------------------
__global__ void __launch_bounds__(256) gather1_kernel(
    const int* __restrict__ idxw, const int* __restrict__ flag,
    const __hip_bfloat16* __restrict__ x1,    // [BN,64]
    __hip_bfloat16* __restrict__ x2)          // [BN,128]
{
    int t = blockIdx.x * 256 + threadIdx.x;
    int p = t >> 3, j = t & 7;
    if (p >= BN) return;
    int dual = (*flag == 0) ? 2 : 1;
    int base = (p >= NPTS) ? NPTS : 0;
    const int* ip = idxw + (size_t)p * KNN * dual;
    float acc[8];
#pragma unroll
    for (int i = 0; i < 8; ++i) acc[i] = 0.f;
#pragma unroll
    for (int k = 0; k < KNN; ++k) {
        int row = base + ip[k * dual];
        bf16x8 v = *(const bf16x8*)((const short*)x1 + (size_t)row * 64 + j * 8);
#pragma unroll
        for (int i = 0; i < 8; ++i) acc[i] += bs2f(v[i]);
    }
    bf16x8 o;
#pragma unroll
    for (int i = 0; i < 8; ++i) o[i] = f2bs(acc[i] * (1.f/16.f));
    *(bf16x8*)((short*)x2 + (size_t)p * 128 + 64 + j * 8) = o;
}

// ---------------------------------------------------------------------------
// gather-mean of x2 rows -> x3[:,128:256]. 16 lanes/point, bf16x8 loads.
// ---------------------------------------------------------------------------
__global__ void __launch_bounds__(256) gather2_kernel(
    const int* __restrict__ idxw, const int* __restrict__ flag,
    const __hip_bfloat16* __restrict__ x2,    // [BN,128]
    __hip_bfloat16* __restrict__ x3)          // [BN,256]
{
    int t = blockIdx.x * 256 + threadIdx.x;
    int p = t >> 4, j = t & 15;
    if (p >= BN) return;
    int dual = (*flag == 0) ? 2 : 1;
    int base = (p >= NPTS) ? NPTS : 0;
    const int* ip = idxw + (size_t)p * KNN * dual;
    float acc[8];
#pragma unroll
    for (int i = 0; i < 8; ++i) acc[i] = 0.f;
#pragma unroll
    for (int k = 0; k < KNN; ++k) {
        int row = base + ip[k * dual];
        bf16x8 v = *(const bf16x8*)((const short*)x2 + (size_t)row * 128 + j * 8);
#pragma unroll
        for (int i = 0; i < 8; ++i) acc[i] += bs2f(v[i]);
    }
    bf16x8 o;
#pragma unroll
    for (int i = 0; i < 8; ++i) o[i] = f2bs(acc[i] * (1.f/16.f));
    *(bf16x8*)((short*)x3 + (size_t)p * 256 + 128 + j * 8) = o;
}

// ---------------------------------------------------------------------------
// Convert W_fin + W_id (fp32 [256,256]) to bf16 into the dead x1 region.
// Runs after gather1 (x1 dead), before final_mfma.
// ---------------------------------------------------------------------------
__global__ void __launch_bounds__(256) conv_w_kernel(
    const float* __restrict__ Wf, const float* __restrict__ Wi,
    short* __restrict__ Wfb, short* __restrict__ Wib)
{
    int t = blockIdx.x * 256 + threadIdx.x;     // 32768 float4 total
    if (t >= 32768) return;
    const float4 v = (t < 16384) ? ((const float4*)Wf)[t] : ((const float4*)Wi)[t - 16384];
    short4 o;
    o.x = f2bs(v.x); o.y = f2bs(v.y); o.z = f2bs(v.z); o.w = f2bs(v.w);
    if (t < 16384) ((short4*)Wfb)[t] = o;
    else           ((short4*)Wib)[t - 16384] = o;
}

// ---------------------------------------------------------------------------
// out = LR(x3 @ Wf^T + bf) + LR(input @ Wi^T + bi), fp32 out. MFMA.
// Block = 16 rows x full N=256 (unique A-fetch). The 16 A-rows (X3 bf16,
// RES->bf16) staged once into LDS (+8-short row pad => <=2-way bank alias,
// free). 4 waves x 64 cols, acc = 32 VGPRs/wave. Grid 2500 (~10 blk/CU).
// Weights stream from L2 (640 MB aggregate @34.5 TB/s ~ 18.5 us, overlapped).
// ---------------------------------------------------------------------------
__global__ void __launch_bounds__(256) final_mfma(
    const __hip_bfloat16* __restrict__ X3,    // [BN,256] bf16 ws
    const float* __restrict__ RES,            // [BN,256] fp32
    const short* __restrict__ Wfb,            // [256,256] bf16
    const float* __restrict__ Bf,             // [256]
    const short* __restrict__ Wib,            // [256,256] bf16
    const float* __restrict__ Bi,             // [256]
    float* __restrict__ OUT)                  // [BN,256] fp32
{
    __shared__ short a3[16][264];             // X3 rows (264 = 256 + 8 pad)
    __shared__ short ar[16][264];             // RES rows (bf16)
    int t = threadIdx.x;
    int p0 = blockIdx.x * 16;
    {
        int row = t >> 4, c0 = (t & 15) * 16;
        const short* src = (const short*)X3 + (size_t)(p0 + row) * DIM + c0;
        *(bf16x8*)&a3[row][c0]     = *(const bf16x8*)(src);
        *(bf16x8*)&a3[row][c0 + 8] = *(const bf16x8*)(src + 8);
        const float* rsrc = RES + (size_t)(p0 + row) * DIM + c0;
        bf16x8 r0 = ldf32_bf16x8(rsrc);
        bf16x8 r1 = ldf32_bf16x8(rsrc + 8);
        *(bf16x8*)&ar[row][c0]     = r0;
        *(bf16x8*)&ar[row][c0 + 8] = r1;
    }
    __syncthreads();

    int wave = t >> 6, lane = t & 63;
    int r = lane & 15, q = lane >> 4;
    int n0 = wave * 64;
    const short* Wf0 = Wfb + (size_t)(n0 + r) * DIM + q * 8;   // + nt*16*DIM + kk*32
    const short* Wi0 = Wib + (size_t)(n0 + r) * DIM + q * 8;

    f32x4 acc1[4], acc2[4];
#pragma unroll
    for (int nt = 0; nt < 4; ++nt) {
        acc1[nt] = (f32x4){0.f,0.f,0.f,0.f};
        acc2[nt] = (f32x4){0.f,0.f,0.f,0.f};
    }
#pragma unroll
    for (int kk = 0; kk < 8; ++kk) {
        bf16x8 a1 = *(const bf16x8*)&a3[r][kk * 32 + q * 8];
        bf16x8 a2 = *(const bf16x8*)&ar[r][kk * 32 + q * 8];
#pragma unroll
        for (int nt = 0; nt < 4; ++nt) {
            bf16x8 b1 = *(const bf16x8*)(Wf0 + (size_t)nt * (16 * DIM) + kk * 32);
            bf16x8 b2 = *(const bf16x8*)(Wi0 + (size_t)nt * (16 * DIM) + kk * 32);
            acc1[nt] = __builtin_amdgcn_mfma_f32_16x16x32_bf16(a1, b1, acc1[nt], 0, 0, 0);
            acc2[nt] = __builtin_amdgcn_mfma_f32_16x16x32_bf16(a2, b2, acc2[nt], 0, 0, 0);
        }
    }
#pragma unroll
    for (int nt = 0; nt < 4; ++nt) {
        int col = n0 + nt * 16 + r;
        float bfv = Bf[col], biv = Bi[col];
#pragma unroll
        for (int i = 0; i < 4; ++i) {
            float v = lrelu(acc1[nt][i] + bfv) + lrelu(acc2[nt][i] + biv);
            OUT[(size_t)(p0 + q*4 + i) * DIM + col] = v;
        }
    }
}

// ---------------------------------------------------------------------------
extern "C" void kernel_launch(void* const* d_in, const int* in_sizes, int n_in,
                              void* d_out, int out_size, void* d_ws, size_t ws_size,
                              hipStream_t stream)
{
    const float* input  = (const float*)d_in[0];   // [2,20000,256]
    const float* geom   = (const float*)d_in[1];   // [2,20000,16,4]
    const int*   idxw   = (const int*)d_in[2];     // int32/int64 (detected)
    const float* W_init = (const float*)d_in[3];   // [64,256]
    const float* b_init = (const float*)d_in[4];
    const float* W_l1   = (const float*)d_in[5];   // [64,4]
    const float* b_l1   = (const float*)d_in[6];
    const float* W_l2   = (const float*)d_in[7];   // [128,4]
    const float* b_l2   = (const float*)d_in[8];
    const float* W_fin  = (const float*)d_in[9];   // [256,256]
    const float* b_fin  = (const float*)d_in[10];
    const float* W_id   = (const float*)d_in[11];  // [256,256]
    const float* b_id   = (const float*)d_in[12];
    float* out = (float*)d_out;                    // [2,20000,256] fp32

    // ws (proven <= 35.84 MB OK in R4-R6):
    //   flag @0 (16B)
    //   x1  [BN,64]  bf16 @16            — dead after gather1; conv_w reuses it
    //   x2  [BN,128] bf16 @16+5.12e6
    //   x3  [BN,256] bf16 @16+15.36e6
    char* ws = (char*)d_ws;
    int* flag = (int*)ws;
    __hip_bfloat16* x1 = (__hip_bfloat16*)(ws + 16);
    __hip_bfloat16* x2 = (__hip_bfloat16*)(ws + 16 + 5120000);
    __hip_bfloat16* x3 = (__hip_bfloat16*)(ws + 16 + 15360000);
    short* Wfb = (short*)(ws + 16);                 // 131072 B
    short* Wib = (short*)(ws + 16 + 131072);        // 131072 B  (within old x1)

    geom_kernel<<<1876, 256, 0, stream>>>(geom, W_l1, b_l1, W_l2, b_l2,
                                          idxw, flag, x2, x3);
    mlp_init_mfma<<<625, 256, 0, stream>>>(input, W_init, b_init, x1);
    gather1_kernel<<<1250, 256, 0, stream>>>(idxw, flag, x1, x2);
    gather2_kernel<<<2500, 256, 0, stream>>>(idxw, flag, x2, x3);
    conv_w_kernel<<<128, 256, 0, stream>>>(W_fin, W_id, Wfb, Wib);
    final_mfma<<<2500, 256, 0, stream>>>(x3, input, Wfb, b_fin, Wib, b_id, out);
}

// Round 8
// 274.246 us; speedup vs baseline: 2.2649x; 1.0742x over previous
//
#include <hip/hip_runtime.h>
#include <hip/hip_bf16.h>

// Problem constants (reference: B=2, N=20000, K=16, DIM=256)
// Established facts (R1-R7):
//   - float tensors fp32; idx int32/int64 runtime-detected; d_out fp32
//   - MFMA 16x16x32_bf16 gemm-BT fragments + C/D map verified
//   - R5: >=128 acc VGPRs/wave -> latency-bound; 32-64 acc is fine
//   - R6: N-split across blocks re-fetches A 4x -> keep full-N blocks
//   - R7: 64 weight loads vs 64 MFMA per wave still latency-bound ->
//     this round: b-frag register reuse over 2 m-subtiles (128 MFMA / 64 loads)
#define BN   40000
#define NPTS 20000
#define KNN  16
#define DIM  256

typedef __attribute__((ext_vector_type(8))) short bf16x8;   // 8 bf16 = 4 VGPRs
typedef __attribute__((ext_vector_type(4))) float f32x4;

__device__ __forceinline__ float lrelu(float v) { return v > 0.f ? v : 0.1f * v; }
__device__ __forceinline__ float bs2f(short s) {
    union { unsigned u; float f; } c; c.u = ((unsigned)(unsigned short)s) << 16;
    return c.f;
}
__device__ __forceinline__ short f2bs(float f) {
    __hip_bfloat16 h = __float2bfloat16(f);           // RNE
    return *reinterpret_cast<short*>(&h);
}
__device__ __forceinline__ bf16x8 ldf32_bf16x8(const float* p) {
    const float4 a = ((const float4*)p)[0];
    const float4 b = ((const float4*)p)[1];
    bf16x8 r;
    r[0]=f2bs(a.x); r[1]=f2bs(a.y); r[2]=f2bs(a.z); r[3]=f2bs(a.w);
    r[4]=f2bs(b.x); r[5]=f2bs(b.y); r[6]=f2bs(b.z); r[7]=f2bs(b.w);
    return r;
}

// ---------------------------------------------------------------------------
// geom MLPs + idx-dtype detect (block 1875) + weight conversion (1876..2019).
// geom: 12 threads/point, 16 channels each. cg<4 -> x2[:,0:64]; else x3[:,0:128].
// conv: Wf,Wi,W_init fp32 -> bf16 into ws (runs first, region never clobbered).
// ---------------------------------------------------------------------------
__global__ void __launch_bounds__(256) geom_kernel(
    const float* __restrict__ geom,      // [BN,16,4]
    const float* __restrict__ W1, const float* __restrict__ B1,   // [64,4],[64]
    const float* __restrict__ W2, const float* __restrict__ B2,   // [128,4],[128]
    const int* __restrict__ idxw, int* __restrict__ flag,
    const float* __restrict__ Wf, const float* __restrict__ Wi,   // [256,256]
    const float* __restrict__ Wn,                                  // [64,256]
    short* __restrict__ Wfb, short* __restrict__ Wib, short* __restrict__ Wnb,
    __hip_bfloat16* __restrict__ x2,     // [BN,128]
    __hip_bfloat16* __restrict__ x3)     // [BN,256]
{
    if (blockIdx.x >= 1876) {            // ---- weight-convert blocks ----
        int t = (blockIdx.x - 1876) * 256 + threadIdx.x;   // < 36864
        if (t >= 36864) return;
        float4 v; short4* dst;
        if (t < 16384)      { v = ((const float4*)Wf)[t];         dst = (short4*)Wfb + t; }
        else if (t < 32768) { v = ((const float4*)Wi)[t - 16384]; dst = (short4*)Wib + (t - 16384); }
        else                { v = ((const float4*)Wn)[t - 32768]; dst = (short4*)Wnb + (t - 32768); }
        short4 o; o.x = f2bs(v.x); o.y = f2bs(v.y); o.z = f2bs(v.z); o.w = f2bs(v.w);
        *dst = o;
        return;
    }
    if (blockIdx.x == 1875) {            // ---- detect block (no atomics) ----
        __shared__ int red[256];
        int t = threadIdx.x;
        int v = 0;
#pragma unroll
        for (int it = 0; it < 64; ++it)
            v |= idxw[2 * (t + it * 256) + 1];       // odd words, first 128 KB
        red[t] = v;
        __syncthreads();
        for (int s = 128; s > 0; s >>= 1) {
            if (t < s) red[t] |= red[t + s];
            __syncthreads();
        }
        if (t == 0) *flag = (red[0] != 0) ? 1 : 0;
        return;
    }
    int tid = blockIdx.x * 256 + threadIdx.x;        // < 480000 exactly
    int p  = tid / 12;
    int cg = tid - p * 12;               // 0..11 -> 16 channels each
    const float4* g = (const float4*)(geom + (size_t)p * (KNN * 4));
    const float4* Wp; const float* Bp; int c0;
    if (cg < 4) { c0 = cg * 16;       Wp = (const float4*)W1; Bp = B1; }
    else        { c0 = (cg - 4) * 16; Wp = (const float4*)W2; Bp = B2; }
    float4 w[16]; float bb[16];
#pragma unroll
    for (int j = 0; j < 16; ++j) { w[j] = Wp[c0 + j]; bb[j] = Bp[c0 + j]; }
    float acc[16];
#pragma unroll
    for (int j = 0; j < 16; ++j) acc[j] = 0.f;
#pragma unroll
    for (int k = 0; k < KNN; ++k) {
        float4 gv = g[k];
#pragma unroll
        for (int j = 0; j < 16; ++j)
            acc[j] += lrelu(bb[j] + gv.x*w[j].x + gv.y*w[j].y + gv.z*w[j].z + gv.w*w[j].w);
    }
    const float s = 1.f/16.f;
    short* dst = (cg < 4) ? ((short*)x2 + (size_t)p*128 + c0)
                          : ((short*)x3 + (size_t)p*256 + c0);
    bf16x8 o0, o1;
#pragma unroll
    for (int j = 0; j < 8; ++j) { o0[j] = f2bs(acc[j] * s); o1[j] = f2bs(acc[j+8] * s); }
    *(bf16x8*)(dst)     = o0;
    *(bf16x8*)(dst + 8) = o1;
}

// ---------------------------------------------------------------------------
// x1 = LR(input @ W_init^T + b_init), MFMA, bf16 pre-converted weights.
// Block = 64 rows (4 waves x 16); wave covers all 64 n (4 nt). Grid 625.
// x1 lives in d_out scratch (dead before final_mfma rewrites d_out).
// ---------------------------------------------------------------------------
__global__ void __launch_bounds__(256) mlp_init_mfma(
    const float* __restrict__ X,     // [BN,256]
    const short* __restrict__ Wnb,   // [64,256] bf16
    const float* __restrict__ bias,  // [64]
    __hip_bfloat16* __restrict__ Y)  // [BN,64] bf16 (d_out scratch)
{
    int wave = threadIdx.x >> 6, lane = threadIdx.x & 63;
    int r = lane & 15, q = lane >> 4;
    int m0 = blockIdx.x * 64 + wave * 16;
    const float* Xs = X + (size_t)(m0 + r) * DIM + q * 8;
    const short* W0 = Wnb + (size_t)r * DIM + q * 8;   // + nt*16*DIM + kk*32
    f32x4 acc[4];
#pragma unroll
    for (int nt = 0; nt < 4; ++nt) acc[nt] = (f32x4){0.f,0.f,0.f,0.f};
#pragma unroll
    for (int kk = 0; kk < 8; ++kk) {
        bf16x8 a = ldf32_bf16x8(Xs + kk * 32);
#pragma unroll
        for (int nt = 0; nt < 4; ++nt) {
            bf16x8 b = *(const bf16x8*)(W0 + (size_t)nt * (16 * DIM) + kk * 32);
            acc[nt] = __builtin_amdgcn_mfma_f32_16x16x32_bf16(a, b, acc[nt], 0, 0, 0);
        }
    }
#pragma unroll
    for (int nt = 0; nt < 4; ++nt) {
        int col = nt * 16 + r;
        float bv = bias[col];
#pragma unroll
        for (int i = 0; i < 4; ++i) {
            float v = lrelu(acc[nt][i] + bv);
            Y[(size_t)(m0 + q*4 + i) * 64 + col] = __float2bfloat16(v);
        }
    }
}

// ---------------------------------------------------------------------------
// gather-mean of x1 rows -> x2[:,64:128]. 8 lanes/point, bf16x8 loads.
// ---------------------------------------------------------------------------
__global__ void __launch_bounds__(256) gather1_kernel(
    const int* __restrict__ idxw, const int* __restrict__ flag,
    const __hip_bfloat16* __restrict__ x1,    // [BN,64]
    __hip_bfloat16* __restrict__ x2)          // [BN,128]
{
    int t = blockIdx.x * 256 + threadIdx.x;
    int p = t >> 3, j = t & 7;
    if (p >= BN) return;
    int dual = (*flag == 0) ? 2 : 1;
    int base = (p >= NPTS) ? NPTS : 0;
    const int* ip = idxw + (size_t)p * KNN * dual;
    float acc[8];
#pragma unroll
    for (int i = 0; i < 8; ++i) acc[i] = 0.f;
#pragma unroll
    for (int k = 0; k < KNN; ++k) {
        int row = base + ip[k * dual];
        bf16x8 v = *(const bf16x8*)((const short*)x1 + (size_t)row * 64 + j * 8);
#pragma unroll
        for (int i = 0; i < 8; ++i) acc[i] += bs2f(v[i]);
    }
    bf16x8 o;
#pragma unroll
    for (int i = 0; i < 8; ++i) o[i] = f2bs(acc[i] * (1.f/16.f));
    *(bf16x8*)((short*)x2 + (size_t)p * 128 + 64 + j * 8) = o;
}

// ---------------------------------------------------------------------------
// gather-mean of x2 rows -> x3[:,128:256]. 16 lanes/point, bf16x8 loads.
// ---------------------------------------------------------------------------
__global__ void __launch_bounds__(256) gather2_kernel(
    const int* __restrict__ idxw, const int* __restrict__ flag,
    const __hip_bfloat16* __restrict__ x2,    // [BN,128]
    __hip_bfloat16* __restrict__ x3)          // [BN,256]
{
    int t = blockIdx.x * 256 + threadIdx.x;
    int p = t >> 4, j = t & 15;
    if (p >= BN) return;
    int dual = (*flag == 0) ? 2 : 1;
    int base = (p >= NPTS) ? NPTS : 0;
    const int* ip = idxw + (size_t)p * KNN * dual;
    float acc[8];
#pragma unroll
    for (int i = 0; i < 8; ++i) acc[i] = 0.f;
#pragma unroll
    for (int k = 0; k < KNN; ++k) {
        int row = base + ip[k * dual];
        bf16x8 v = *(const bf16x8*)((const short*)x2 + (size_t)row * 128 + j * 8);
#pragma unroll
        for (int i = 0; i < 8; ++i) acc[i] += bs2f(v[i]);
    }
    bf16x8 o;
#pragma unroll
    for (int i = 0; i < 8; ++i) o[i] = f2bs(acc[i] * (1.f/16.f));
    *(bf16x8*)((short*)x3 + (size_t)p * 256 + 128 + j * 8) = o;
}

// ---------------------------------------------------------------------------
// out = LR(x3 @ Wf^T + bf) + LR(input @ Wi^T + bi), fp32 out. MFMA.
// Block = 32 rows x full N=256 (unique A-fetch, LDS-staged). Wave = 2
// m-subtiles x 64 cols x 2 GEMMs: each b-frag loaded once, used 2x ->
// 128 MFMA vs 64 weight loads/wave (2x R7 ratio). acc = 64 VGPRs. Grid 1250.
// ---------------------------------------------------------------------------
__global__ void __launch_bounds__(256, 4) final_mfma(
    const __hip_bfloat16* __restrict__ X3,    // [BN,256] bf16 ws
    const float* __restrict__ RES,            // [BN,256] fp32
    const short* __restrict__ Wfb,            // [256,256] bf16
    const float* __restrict__ Bf,             // [256]
    const short* __restrict__ Wib,            // [256,256] bf16
    const float* __restrict__ Bi,             // [256]
    float* __restrict__ OUT)                  // [BN,256] fp32
{
    __shared__ short a3[32][264];             // X3 rows (264 = 256 + 8 pad)
    __shared__ short ar[32][264];             // RES rows (bf16)
    int t = threadIdx.x;
    int p0 = blockIdx.x * 32;
    {
        int row = t >> 3, c0 = (t & 7) * 32;  // 32 channels per thread
        const short* src = (const short*)X3 + (size_t)(p0 + row) * DIM + c0;
        const float* rsrc = RES + (size_t)(p0 + row) * DIM + c0;
#pragma unroll
        for (int u = 0; u < 4; ++u) {
            *(bf16x8*)&a3[row][c0 + u * 8] = *(const bf16x8*)(src + u * 8);
            *(bf16x8*)&ar[row][c0 + u * 8] = ldf32_bf16x8(rsrc + u * 8);
        }
    }
    __syncthreads();

    int wave = t >> 6, lane = t & 63;
    int r = lane & 15, q = lane >> 4;
    int n0 = wave * 64;
    const short* Wf0 = Wfb + (size_t)(n0 + r) * DIM + q * 8;   // + nt*16*DIM + kk*32
    const short* Wi0 = Wib + (size_t)(n0 + r) * DIM + q * 8;

    f32x4 acc1[2][4], acc2[2][4];
#pragma unroll
    for (int s = 0; s < 2; ++s)
#pragma unroll
        for (int nt = 0; nt < 4; ++nt) {
            acc1[s][nt] = (f32x4){0.f,0.f,0.f,0.f};
            acc2[s][nt] = (f32x4){0.f,0.f,0.f,0.f};
        }
#pragma unroll
    for (int kk = 0; kk < 8; ++kk) {
        bf16x8 a10 = *(const bf16x8*)&a3[r][kk * 32 + q * 8];
        bf16x8 a11 = *(const bf16x8*)&a3[16 + r][kk * 32 + q * 8];
        bf16x8 a20 = *(const bf16x8*)&ar[r][kk * 32 + q * 8];
        bf16x8 a21 = *(const bf16x8*)&ar[16 + r][kk * 32 + q * 8];
#pragma unroll
        for (int nt = 0; nt < 4; ++nt) {
            bf16x8 b1 = *(const bf16x8*)(Wf0 + (size_t)nt * (16 * DIM) + kk * 32);
            bf16x8 b2 = *(const bf16x8*)(Wi0 + (size_t)nt * (16 * DIM) + kk * 32);
            acc1[0][nt] = __builtin_amdgcn_mfma_f32_16x16x32_bf16(a10, b1, acc1[0][nt], 0, 0, 0);
            acc1[1][nt] = __builtin_amdgcn_mfma_f32_16x16x32_bf16(a11, b1, acc1[1][nt], 0, 0, 0);
            acc2[0][nt] = __builtin_amdgcn_mfma_f32_16x16x32_bf16(a20, b2, acc2[0][nt], 0, 0, 0);
            acc2[1][nt] = __builtin_amdgcn_mfma_f32_16x16x32_bf16(a21, b2, acc2[1][nt], 0, 0, 0);
        }
    }
#pragma unroll
    for (int s = 0; s < 2; ++s)
#pragma unroll
        for (int nt = 0; nt < 4; ++nt) {
            int col = n0 + nt * 16 + r;
            float bfv = Bf[col], biv = Bi[col];
#pragma unroll
            for (int i = 0; i < 4; ++i) {
                float v = lrelu(acc1[s][nt][i] + bfv) + lrelu(acc2[s][nt][i] + biv);
                OUT[(size_t)(p0 + s*16 + q*4 + i) * DIM + col] = v;
            }
        }
}

// ---------------------------------------------------------------------------
extern "C" void kernel_launch(void* const* d_in, const int* in_sizes, int n_in,
                              void* d_out, int out_size, void* d_ws, size_t ws_size,
                              hipStream_t stream)
{
    const float* input  = (const float*)d_in[0];   // [2,20000,256]
    const float* geom   = (const float*)d_in[1];   // [2,20000,16,4]
    const int*   idxw   = (const int*)d_in[2];     // int32/int64 (detected)
    const float* W_init = (const float*)d_in[3];   // [64,256]
    const float* b_init = (const float*)d_in[4];
    const float* W_l1   = (const float*)d_in[5];   // [64,4]
    const float* b_l1   = (const float*)d_in[6];
    const float* W_l2   = (const float*)d_in[7];   // [128,4]
    const float* b_l2   = (const float*)d_in[8];
    const float* W_fin  = (const float*)d_in[9];   // [256,256]
    const float* b_fin  = (const float*)d_in[10];
    const float* W_id   = (const float*)d_in[11];  // [256,256]
    const float* b_id   = (const float*)d_in[12];
    float* out = (float*)d_out;                    // [2,20000,256] fp32

    // ws layout (<= 35.84 MB, proven safe R4-R7):
    //   flag @0 (16B)
    //   weights bf16 @16: Wfb 128KB, Wib 128KB, Wnb 64KB  (written first,
    //     never overwritten — occupies start of former x1 region)
    //   x2  [BN,128] bf16 @16+5.12e6
    //   x3  [BN,256] bf16 @16+15.36e6
    // x1 [BN,64] bf16 lives in d_out scratch (d_out fully rewritten by final).
    char* ws = (char*)d_ws;
    int* flag = (int*)ws;
    short* Wfb = (short*)(ws + 16);
    short* Wib = (short*)(ws + 16 + 131072);
    short* Wnb = (short*)(ws + 16 + 262144);
    __hip_bfloat16* x2 = (__hip_bfloat16*)(ws + 16 + 5120000);
    __hip_bfloat16* x3 = (__hip_bfloat16*)(ws + 16 + 15360000);
    __hip_bfloat16* x1 = (__hip_bfloat16*)d_out;   // scratch, dead before final

    geom_kernel<<<2020, 256, 0, stream>>>(geom, W_l1, b_l1, W_l2, b_l2,
                                          idxw, flag, W_fin, W_id, W_init,
                                          Wfb, Wib, Wnb, x2, x3);
    mlp_init_mfma<<<625, 256, 0, stream>>>(input, Wnb, b_init, x1);
    gather1_kernel<<<1250, 256, 0, stream>>>(idxw, flag, x1, x2);
    gather2_kernel<<<2500, 256, 0, stream>>>(idxw, flag, x2, x3);
    final_mfma<<<1250, 256, 0, stream>>>(x3, input, Wfb, b_fin, Wib, b_id, out);
}

// Round 9
// 235.981 us; speedup vs baseline: 2.6322x; 1.1622x over previous
//
#include <hip/hip_runtime.h>
#include <hip/hip_bf16.h>

// Problem constants (reference: B=2, N=20000, K=16, DIM=256)
// Established facts (R1-R8):
//   - float tensors fp32; idx int32/int64 runtime-detected; d_out fp32
//   - MFMA 16x16x32_bf16 gemm-BT fragments + C/D map verified
//   - R5-R8: compiler emits load->vmcnt(0)->use chains for global->VGPR weight
//     loads (VGPR_Count 56-64, no buffering); per-wave serial time scales with
//     per-wave work, NOT load count => VGPR-result loads are the dead end.
//     This round: m97-style global_load_lds DMA staging of weights.
#define BN   40000
#define NPTS 20000
#define KNN  16
#define DIM  256

typedef __attribute__((ext_vector_type(8))) short bf16x8;   // 8 bf16 = 4 VGPRs
typedef __attribute__((ext_vector_type(4))) float f32x4;

__device__ __forceinline__ float lrelu(float v) { return v > 0.f ? v : 0.1f * v; }
__device__ __forceinline__ float bs2f(short s) {
    union { unsigned u; float f; } c; c.u = ((unsigned)(unsigned short)s) << 16;
    return c.f;
}
__device__ __forceinline__ short f2bs(float f) {
    __hip_bfloat16 h = __float2bfloat16(f);           // RNE
    return *reinterpret_cast<short*>(&h);
}
__device__ __forceinline__ bf16x8 ldf32_bf16x8(const float* p) {
    const float4 a = ((const float4*)p)[0];
    const float4 b = ((const float4*)p)[1];
    bf16x8 r;
    r[0]=f2bs(a.x); r[1]=f2bs(a.y); r[2]=f2bs(a.z); r[3]=f2bs(a.w);
    r[4]=f2bs(b.x); r[5]=f2bs(b.y); r[6]=f2bs(b.z); r[7]=f2bs(b.w);
    return r;
}

// async global->LDS, 16 B per lane. gptr per-lane (base + lane*16 expected),
// lds dst = wave-uniform base + lane*16 (HW scatter).
__device__ __forceinline__ void dma16(const void* g, void* l) {
    __builtin_amdgcn_global_load_lds(
        (const __attribute__((address_space(1))) unsigned int*)g,
        (__attribute__((address_space(3))) unsigned int*)l, 16, 0, 0);
}

// ---------------------------------------------------------------------------
// geom MLPs (blocks 0..3749) + idx-dtype detect (block 3750) + weight
// conversion (blocks 3751..3894).
// geom: 24 threads/point, 8 channels each (w[8] -> ~80 VGPR, high occupancy).
// conv: Wf,Wi -> kk-tiled bf16 Wt[kk][mat][q][n][8] (32 KB contiguous per kk
//       slice, DMA-friendly); W_init -> linear bf16 Wnb.
// detect: single block, no atomics; int64 storage => odd 32-bit words all 0.
// ---------------------------------------------------------------------------
__global__ void __launch_bounds__(256) geom_kernel(
    const float* __restrict__ geom,      // [BN,16,4]
    const float* __restrict__ W1, const float* __restrict__ B1,   // [64,4],[64]
    const float* __restrict__ W2, const float* __restrict__ B2,   // [128,4],[128]
    const int* __restrict__ idxw, int* __restrict__ flag,
    const float* __restrict__ Wf, const float* __restrict__ Wi,   // [256,256]
    const float* __restrict__ Wn,                                  // [64,256]
    short* __restrict__ Wt, short* __restrict__ Wnb,
    __hip_bfloat16* __restrict__ x2,     // [BN,128]
    __hip_bfloat16* __restrict__ x3)     // [BN,256]
{
    if (blockIdx.x >= 3751) {            // ---- weight-convert blocks ----
        int t = (blockIdx.x - 3751) * 256 + threadIdx.x;   // < 36864 exactly
        if (t < 32768) {                 // Wf (t<16384) / Wi -> tiled Wt
            int mat = (t >> 14) & 1;
            int tt  = t & 16383;
            float4 v = mat ? ((const float4*)Wi)[tt] : ((const float4*)Wf)[tt];
            int n  = tt >> 6;
            int k  = (tt & 63) * 4;
            int kk = k >> 5, q = (k >> 3) & 3, j = k & 7;
            short4 o; o.x=f2bs(v.x); o.y=f2bs(v.y); o.z=f2bs(v.z); o.w=f2bs(v.w);
            *(short4*)(Wt + ((size_t)((kk*2 + mat)*4 + q))*2048 + n*8 + j) = o;
        } else {                          // W_init -> linear Wnb
            int tt = t - 32768;           // < 4096
            float4 v = ((const float4*)Wn)[tt];
            short4 o; o.x=f2bs(v.x); o.y=f2bs(v.y); o.z=f2bs(v.z); o.w=f2bs(v.w);
            ((short4*)Wnb)[tt] = o;
        }
        return;
    }
    if (blockIdx.x == 3750) {            // ---- detect block (no atomics) ----
        __shared__ int red[256];
        int t = threadIdx.x;
        int v = 0;
#pragma unroll
        for (int it = 0; it < 64; ++it)
            v |= idxw[2 * (t + it * 256) + 1];       // odd words, first 128 KB
        red[t] = v;
        __syncthreads();
        for (int s = 128; s > 0; s >>= 1) {
            if (t < s) red[t] |= red[t + s];
            __syncthreads();
        }
        if (t == 0) *flag = (red[0] != 0) ? 1 : 0;
        return;
    }
    // ---- geom blocks: 3750 x 256 = 960000 threads = 40000 pts x 24 ----
    int tid = blockIdx.x * 256 + threadIdx.x;
    int p  = tid / 24;
    int cg = tid - p * 24;               // 0..23 -> 8 channels each
    const float4* g = (const float4*)(geom + (size_t)p * (KNN * 4));
    const float4* Wp; const float* Bp; int c0;
    if (cg < 8) { c0 = cg * 8;       Wp = (const float4*)W1; Bp = B1; }
    else        { c0 = (cg - 8) * 8; Wp = (const float4*)W2; Bp = B2; }
    float4 w[8]; float bb[8];
#pragma unroll
    for (int j = 0; j < 8; ++j) { w[j] = Wp[c0 + j]; bb[j] = Bp[c0 + j]; }
    float acc[8];
#pragma unroll
    for (int j = 0; j < 8; ++j) acc[j] = 0.f;
#pragma unroll
    for (int k = 0; k < KNN; ++k) {
        float4 gv = g[k];
#pragma unroll
        for (int j = 0; j < 8; ++j)
            acc[j] += lrelu(bb[j] + gv.x*w[j].x + gv.y*w[j].y + gv.z*w[j].z + gv.w*w[j].w);
    }
    const float s = 1.f/16.f;
    short* dst = (cg < 8) ? ((short*)x2 + (size_t)p*128 + c0)
                          : ((short*)x3 + (size_t)p*256 + c0);
    bf16x8 o;
#pragma unroll
    for (int j = 0; j < 8; ++j) o[j] = f2bs(acc[j] * s);
    *(bf16x8*)dst = o;
}

// ---------------------------------------------------------------------------
// x1 = LR(input @ W_init^T + b_init), MFMA, bf16 pre-converted weights.
// Block = 64 rows (4 waves x 16); wave covers all 64 n (4 nt). Grid 625.
// x1 lives in d_out scratch (dead before final_mfma rewrites d_out).
// ---------------------------------------------------------------------------
__global__ void __launch_bounds__(256) mlp_init_mfma(
    const float* __restrict__ X,     // [BN,256]
    const short* __restrict__ Wnb,   // [64,256] bf16
    const float* __restrict__ bias,  // [64]
    __hip_bfloat16* __restrict__ Y)  // [BN,64] bf16 (d_out scratch)
{
    int wave = threadIdx.x >> 6, lane = threadIdx.x & 63;
    int r = lane & 15, q = lane >> 4;
    int m0 = blockIdx.x * 64 + wave * 16;
    const float* Xs = X + (size_t)(m0 + r) * DIM + q * 8;
    const short* W0 = Wnb + (size_t)r * DIM + q * 8;   // + nt*16*DIM + kk*32
    f32x4 acc[4];
#pragma unroll
    for (int nt = 0; nt < 4; ++nt) acc[nt] = (f32x4){0.f,0.f,0.f,0.f};
#pragma unroll
    for (int kk = 0; kk < 8; ++kk) {
        bf16x8 a = ldf32_bf16x8(Xs + kk * 32);
#pragma unroll
        for (int nt = 0; nt < 4; ++nt) {
            bf16x8 b = *(const bf16x8*)(W0 + (size_t)nt * (16 * DIM) + kk * 32);
            acc[nt] = __builtin_amdgcn_mfma_f32_16x16x32_bf16(a, b, acc[nt], 0, 0, 0);
        }
    }
#pragma unroll
    for (int nt = 0; nt < 4; ++nt) {
        int col = nt * 16 + r;
        float bv = bias[col];
#pragma unroll
        for (int i = 0; i < 4; ++i) {
            float v = lrelu(acc[nt][i] + bv);
            Y[(size_t)(m0 + q*4 + i) * 64 + col] = __float2bfloat16(v);
        }
    }
}

// ---------------------------------------------------------------------------
// gather-mean of x1 rows -> x2[:,64:128]. 8 lanes/point, bf16x8 loads.
// ---------------------------------------------------------------------------
__global__ void __launch_bounds__(256) gather1_kernel(
    const int* __restrict__ idxw, const int* __restrict__ flag,
    const __hip_bfloat16* __restrict__ x1,    // [BN,64]
    __hip_bfloat16* __restrict__ x2)          // [BN,128]
{
    int t = blockIdx.x * 256 + threadIdx.x;
    int p = t >> 3, j = t & 7;
    if (p >= BN) return;
    int dual = (*flag == 0) ? 2 : 1;
    int base = (p >= NPTS) ? NPTS : 0;
    const int* ip = idxw + (size_t)p * KNN * dual;
    float acc[8];
#pragma unroll
    for (int i = 0; i < 8; ++i) acc[i] = 0.f;
#pragma unroll
    for (int k = 0; k < KNN; ++k) {
        int row = base + ip[k * dual];
        bf16x8 v = *(const bf16x8*)((const short*)x1 + (size_t)row * 64 + j * 8);
#pragma unroll
        for (int i = 0; i < 8; ++i) acc[i] += bs2f(v[i]);
    }
    bf16x8 o;
#pragma unroll
    for (int i = 0; i < 8; ++i) o[i] = f2bs(acc[i] * (1.f/16.f));
    *(bf16x8*)((short*)x2 + (size_t)p * 128 + 64 + j * 8) = o;
}

// ---------------------------------------------------------------------------
// gather-mean of x2 rows -> x3[:,128:256]. 16 lanes/point, bf16x8 loads.
// ---------------------------------------------------------------------------
__global__ void __launch_bounds__(256) gather2_kernel(
    const int* __restrict__ idxw, const int* __restrict__ flag,
    const __hip_bfloat16* __restrict__ x2,    // [BN,128]
    __hip_bfloat16* __restrict__ x3)          // [BN,256]
{
    int t = blockIdx.x * 256 + threadIdx.x;
    int p = t >> 4, j = t & 15;
    if (p >= BN) return;
    int dual = (*flag == 0) ? 2 : 1;
    int base = (p >= NPTS) ? NPTS : 0;
    const int* ip = idxw + (size_t)p * KNN * dual;
    float acc[8];
#pragma unroll
    for (int i = 0; i < 8; ++i) acc[i] = 0.f;
#pragma unroll
    for (int k = 0; k < KNN; ++k) {
        int row = base + ip[k * dual];
        bf16x8 v = *(const bf16x8*)((const short*)x2 + (size_t)row * 128 + j * 8);
#pragma unroll
        for (int i = 0; i < 8; ++i) acc[i] += bs2f(v[i]);
    }
    bf16x8 o;
#pragma unroll
    for (int i = 0; i < 8; ++i) o[i] = f2bs(acc[i] * (1.f/16.f));
    *(bf16x8*)((short*)x3 + (size_t)p * 256 + 128 + j * 8) = o;
}

// ---------------------------------------------------------------------------
// out = LR(x3 @ Wf^T + bf) + LR(input @ Wi^T + bi), fp32 out. MFMA.
// Block = 16 rows x full N=256, 4 waves x 64 cols. A-frags (both matrices,
// all 8 kk) per-lane in registers (one-time burst). Weights DMA'd per kk
// (32 KB tiled slice) into LDS via global_load_lds; ds_read b-frags are
// 2-way bank-aliased (free). m97 2-barrier K-loop; 32.8 KB LDS -> 3-4
// blocks/CU co-resident hide barrier drains. Grid 2500.
// ---------------------------------------------------------------------------
__global__ void __launch_bounds__(256) final_mfma(
    const __hip_bfloat16* __restrict__ X3,    // [BN,256] bf16 ws
    const float* __restrict__ RES,            // [BN,256] fp32
    const short* __restrict__ Wt,             // tiled bf16 [kk][mat][q][n][8]
    const float* __restrict__ Bf,             // [256]
    const float* __restrict__ Bi,             // [256]
    float* __restrict__ OUT)                  // [BN,256] fp32
{
    __shared__ short wbuf[16384];             // 32 KB: one kk slice, both mats
    int t = threadIdx.x;
    int wave = t >> 6, lane = t & 63;
    int r = lane & 15, q = lane >> 4;
    int p0 = blockIdx.x * 16;

    // issue DMA for kk=0 first (overlaps the A-register burst below)
    const char* WtB = (const char*)Wt;
    char* wbufB = (char*)wbuf;
    {
        const char* src0 = WtB + (size_t)0 * 32768 + wave * 1024 + lane * 16;
#pragma unroll
        for (int rd = 0; rd < 8; ++rd)
            dma16(src0 + rd * 4096, wbufB + rd * 4096 + wave * 1024);
    }

    // A-fragments for all 8 kk, both matrices, in registers
    bf16x8 a1f[8], a2f[8];
    {
        const short* x3r = (const short*)X3 + (size_t)(p0 + r) * DIM + q * 8;
        const float* rsr = RES + (size_t)(p0 + r) * DIM + q * 8;
#pragma unroll
        for (int kk = 0; kk < 8; ++kk) {
            a1f[kk] = *(const bf16x8*)(x3r + kk * 32);
            a2f[kk] = ldf32_bf16x8(rsr + kk * 32);
        }
    }

    f32x4 acc1[4], acc2[4];
#pragma unroll
    for (int nt = 0; nt < 4; ++nt) {
        acc1[nt] = (f32x4){0.f,0.f,0.f,0.f};
        acc2[nt] = (f32x4){0.f,0.f,0.f,0.f};
    }

#pragma unroll
    for (int kk = 0; kk < 8; ++kk) {
        __syncthreads();                  // drain DMA(kk) -> wbuf ready
#pragma unroll
        for (int nt = 0; nt < 4; ++nt) {
            int n = wave * 64 + nt * 16 + r;
            bf16x8 b1 = *(const bf16x8*)&wbuf[(size_t)q * 2048 + n * 8];
            bf16x8 b2 = *(const bf16x8*)&wbuf[(size_t)(4 + q) * 2048 + n * 8];
            acc1[nt] = __builtin_amdgcn_mfma_f32_16x16x32_bf16(a1f[kk], b1, acc1[nt], 0, 0, 0);
            acc2[nt] = __builtin_amdgcn_mfma_f32_16x16x32_bf16(a2f[kk], b2, acc2[nt], 0, 0, 0);
        }
        if (kk < 7) {
            __syncthreads();              // all waves done reading wbuf
            const char* src = WtB + (size_t)(kk + 1) * 32768 + wave * 1024 + lane * 16;
#pragma unroll
            for (int rd = 0; rd < 8; ++rd)
                dma16(src + rd * 4096, wbufB + rd * 4096 + wave * 1024);
        }
    }

#pragma unroll
    for (int nt = 0; nt < 4; ++nt) {
        int col = wave * 64 + nt * 16 + r;
        float bfv = Bf[col], biv = Bi[col];
#pragma unroll
        for (int i = 0; i < 4; ++i) {
            float v = lrelu(acc1[nt][i] + bfv) + lrelu(acc2[nt][i] + biv);
            OUT[(size_t)(p0 + q*4 + i) * DIM + col] = v;
        }
    }
}

// ---------------------------------------------------------------------------
extern "C" void kernel_launch(void* const* d_in, const int* in_sizes, int n_in,
                              void* d_out, int out_size, void* d_ws, size_t ws_size,
                              hipStream_t stream)
{
    const float* input  = (const float*)d_in[0];   // [2,20000,256]
    const float* geom   = (const float*)d_in[1];   // [2,20000,16,4]
    const int*   idxw   = (const int*)d_in[2];     // int32/int64 (detected)
    const float* W_init = (const float*)d_in[3];   // [64,256]
    const float* b_init = (const float*)d_in[4];
    const float* W_l1   = (const float*)d_in[5];   // [64,4]
    const float* b_l1   = (const float*)d_in[6];
    const float* W_l2   = (const float*)d_in[7];   // [128,4]
    const float* b_l2   = (const float*)d_in[8];
    const float* W_fin  = (const float*)d_in[9];   // [256,256]
    const float* b_fin  = (const float*)d_in[10];
    const float* W_id   = (const float*)d_in[11];  // [256,256]
    const float* b_id   = (const float*)d_in[12];
    float* out = (float*)d_out;                    // [2,20000,256] fp32

    // ws layout (<= 35.84 MB, proven safe R4-R8):
    //   flag @0 (16B)
    //   Wt  tiled bf16 256KB @16 ; Wnb linear bf16 64KB @16+262144
    //   x2  [BN,128] bf16 @16+5.12e6
    //   x3  [BN,256] bf16 @16+15.36e6
    // x1 [BN,64] bf16 lives in d_out scratch (d_out fully rewritten by final).
    char* ws = (char*)d_ws;
    int* flag = (int*)ws;
    short* Wt  = (short*)(ws + 16);
    short* Wnb = (short*)(ws + 16 + 262144);
    __hip_bfloat16* x2 = (__hip_bfloat16*)(ws + 16 + 5120000);
    __hip_bfloat16* x3 = (__hip_bfloat16*)(ws + 16 + 15360000);
    __hip_bfloat16* x1 = (__hip_bfloat16*)d_out;   // scratch, dead before final

    geom_kernel<<<3895, 256, 0, stream>>>(geom, W_l1, b_l1, W_l2, b_l2,
                                          idxw, flag, W_fin, W_id, W_init,
                                          Wt, Wnb, x2, x3);
    mlp_init_mfma<<<625, 256, 0, stream>>>(input, Wnb, b_init, x1);
    gather1_kernel<<<1250, 256, 0, stream>>>(idxw, flag, x1, x2);
    gather2_kernel<<<2500, 256, 0, stream>>>(idxw, flag, x2, x3);
    final_mfma<<<2500, 256, 0, stream>>>(x3, input, Wt, b_fin, b_id, out);
}